// Round 1
// baseline (221.406 us; speedup 1.0000x reference)
//
#include <hip/hip_runtime.h>
#include <math.h>

#define BLOCK 256
#define WS_W2_F4 512  // float4 index of W2 block inside ws (float offset 2048)

__device__ __forceinline__ float fast_rcp(float v) {
  float r = __builtin_amdgcn_rcpf(v);
  r = r * (2.0f - v * r);  // 1 Newton step -> ~1 ulp
  return r;
}

// round(clip(v/step, lo, hi)) with exact IEEE division (used for weights, once)
__device__ __forceinline__ float quant_div(float v, float step, float lo, float hi) {
  float t = v / step;
  t = fminf(fmaxf(t, lo), hi);
  return rintf(t);
}

// Prepass: quantize weights to integer-valued floats in ws.
// ws[0..2047]   = qW1 transposed: qw1t[k*16 + j] = round(clip(W1[j,k]/wa1))
// ws[2048..2207]= qW2[j*16 + i]  = round(clip(W2[j,i]/wa2))
__global__ void prep_kernel(const float* __restrict__ W1, const float* __restrict__ wa1p,
                            const float* __restrict__ W2, const float* __restrict__ wa2p,
                            float* __restrict__ ws) {
  const int t = threadIdx.x;
  const float wa1 = wa1p[0], wa2 = wa2p[0];
  for (int e = t; e < 2048; e += BLOCK) {
    int k = e >> 4, j = e & 15;
    ws[e] = quant_div(W1[j * 128 + k], wa1, -128.0f, 127.0f);
  }
  if (t < 160) {
    ws[2048 + t] = quant_div(W2[t], wa2, -128.0f, 127.0f);
  }
}

template <bool USE_WS>
__global__ __launch_bounds__(BLOCK)
void net_kernel(const float* __restrict__ x,
                const float* __restrict__ alpha_p, const float* __restrict__ beta_p,
                const float* __restrict__ a1p, const float* __restrict__ a2p,
                const float* __restrict__ a3p,
                const float* __restrict__ W1, const float* __restrict__ b1,
                const float* __restrict__ wa1p,
                const float* __restrict__ W2, const float* __restrict__ b2,
                const float* __restrict__ wa2p,
                const float* __restrict__ ws,
                float* __restrict__ out, int M) {
  __shared__ __align__(16) float smw[2208];
  const float* wsrc;
  if constexpr (USE_WS) {
    wsrc = ws;
  } else {
    // fallback: block-local weight quantize into LDS
    const int t = threadIdx.x;
    const float wa1 = wa1p[0], wa2 = wa2p[0];
    for (int e = t; e < 2048; e += BLOCK) {
      int k = e >> 4, j = e & 15;
      smw[e] = quant_div(W1[j * 128 + k], wa1, -128.0f, 127.0f);
    }
    if (t < 160) smw[2048 + t] = quant_div(W2[t], wa2, -128.0f, 127.0f);
    __syncthreads();
    wsrc = smw;
  }

  const int row = blockIdx.x * BLOCK + threadIdx.x;
  if (row >= M) return;

  const float alpha = alpha_p[0], beta = beta_p[0];
  const float a1 = a1p[0], a2 = a2p[0], a3 = a3p[0];
  const float wa1 = wa1p[0], wa2 = wa2p[0];
  const float inv_a1 = 1.0f / a1;  // IEEE once
  const float inv_a2 = 1.0f / a2;
  const float inv_a3 = 1.0f / a3;
  const float scale1 = a1 * wa1;   // h = scale1 * (int dot) + b1   (dot exact in fp32)
  const float scale2 = a3 * wa2;   // out = scale2 * (int dot) + b2

  const float4* __restrict__ xr = (const float4*)(x + (size_t)row * 128);
  const float4* __restrict__ wt = (const float4*)wsrc;

  float acc[16];
#pragma unroll
  for (int j = 0; j < 16; ++j) acc[j] = 0.0f;

  float w = 1.0f;
#pragma unroll 1
  for (int cc = 0; cc < 4; ++cc) {
    // burst-load this thread's next 128 B of x (one full line group, consumed from regs)
    float4 xb[8];
#pragma unroll
    for (int u = 0; u < 8; ++u) xb[u] = xr[cc * 8 + u];
    const float* xs = (const float*)xb;
#pragma unroll
    for (int kk = 0; kk < 32; ++kk) {
      const int k = cc * 32 + kk;
      // q = round(clip(w/a1, -128, 127))  (integer-valued float)
      float t = w * inv_a1;
      t = fminf(fmaxf(t, -128.0f), 127.0f);
      const float q = rintf(t);
      // wave-uniform weight row (64 B) — scalar-load eligible
      const float4 wr0 = wt[k * 4 + 0];
      const float4 wr1 = wt[k * 4 + 1];
      const float4 wr2 = wt[k * 4 + 2];
      const float4 wr3 = wt[k * 4 + 3];
      acc[0]  = fmaf(q, wr0.x, acc[0]);
      acc[1]  = fmaf(q, wr0.y, acc[1]);
      acc[2]  = fmaf(q, wr0.z, acc[2]);
      acc[3]  = fmaf(q, wr0.w, acc[3]);
      acc[4]  = fmaf(q, wr1.x, acc[4]);
      acc[5]  = fmaf(q, wr1.y, acc[5]);
      acc[6]  = fmaf(q, wr1.z, acc[6]);
      acc[7]  = fmaf(q, wr1.w, acc[7]);
      acc[8]  = fmaf(q, wr2.x, acc[8]);
      acc[9]  = fmaf(q, wr2.y, acc[9]);
      acc[10] = fmaf(q, wr2.z, acc[10]);
      acc[11] = fmaf(q, wr2.w, acc[11]);
      acc[12] = fmaf(q, wr3.x, acc[12]);
      acc[13] = fmaf(q, wr3.y, acc[13]);
      acc[14] = fmaf(q, wr3.z, acc[14]);
      acc[15] = fmaf(q, wr3.w, acc[15]);
      // recurrence: w <- w + alpha/w - beta*x[k]   (errors contract: |dw'/dw| < 1)
      const float xk = xs[kk];
      const float r = fast_rcp(w);
      w = fmaf(alpha, r, w);
      w = fmaf(-beta, xk, w);
    }
  }

  // epilogue: h -> sigmoid -> uq8 -> q8 (all per-lane, register-resident)
  float s3[16];
#pragma unroll
  for (int j = 0; j < 16; ++j) {
    const float h = fmaf(scale1, acc[j], b1[j]);
    const float e = expf(-h);
    const float s = fast_rcp(1.0f + e);
    float t2 = s * inv_a2;
    t2 = fminf(fmaxf(t2, 0.0f), 255.0f);
    const float s2 = rintf(t2) * a2;
    float t3 = s2 * inv_a3;
    t3 = fminf(fmaxf(t3, -128.0f), 127.0f);
    s3[j] = rintf(t3);  // integer-valued float
  }

  // fc2: out[j] = scale2 * sum_i q3[i]*qw2[j][i] + b2[j]  (exact int dot)
  float* __restrict__ orow = out + (size_t)row * 10;
#pragma unroll
  for (int j = 0; j < 10; ++j) {
    const float4 u0 = wt[WS_W2_F4 + j * 4 + 0];
    const float4 u1 = wt[WS_W2_F4 + j * 4 + 1];
    const float4 u2 = wt[WS_W2_F4 + j * 4 + 2];
    const float4 u3 = wt[WS_W2_F4 + j * 4 + 3];
    float a = s3[0] * u0.x;
    a = fmaf(s3[1],  u0.y, a);
    a = fmaf(s3[2],  u0.z, a);
    a = fmaf(s3[3],  u0.w, a);
    a = fmaf(s3[4],  u1.x, a);
    a = fmaf(s3[5],  u1.y, a);
    a = fmaf(s3[6],  u1.z, a);
    a = fmaf(s3[7],  u1.w, a);
    a = fmaf(s3[8],  u2.x, a);
    a = fmaf(s3[9],  u2.y, a);
    a = fmaf(s3[10], u2.z, a);
    a = fmaf(s3[11], u2.w, a);
    a = fmaf(s3[12], u3.x, a);
    a = fmaf(s3[13], u3.y, a);
    a = fmaf(s3[14], u3.z, a);
    a = fmaf(s3[15], u3.w, a);
    orow[j] = fmaf(scale2, a, b2[j]);
  }
}

extern "C" void kernel_launch(void* const* d_in, const int* in_sizes, int n_in,
                              void* d_out, int out_size, void* d_ws, size_t ws_size,
                              hipStream_t stream) {
  const float* x     = (const float*)d_in[0];
  const float* alpha = (const float*)d_in[1];
  const float* beta  = (const float*)d_in[2];
  const float* a1    = (const float*)d_in[3];
  const float* a2    = (const float*)d_in[4];
  const float* a3    = (const float*)d_in[5];
  const float* W1    = (const float*)d_in[6];
  const float* b1    = (const float*)d_in[7];
  const float* wa1   = (const float*)d_in[8];
  const float* W2    = (const float*)d_in[9];
  const float* b2    = (const float*)d_in[10];
  const float* wa2   = (const float*)d_in[11];
  float* out = (float*)d_out;
  const int M = in_sizes[0] / 128;
  const int grid = (M + BLOCK - 1) / BLOCK;
  if (ws_size >= 2208 * sizeof(float)) {
    float* ws = (float*)d_ws;
    prep_kernel<<<1, BLOCK, 0, stream>>>(W1, wa1, W2, wa2, ws);
    net_kernel<true><<<grid, BLOCK, 0, stream>>>(x, alpha, beta, a1, a2, a3,
                                                 W1, b1, wa1, W2, b2, wa2, ws, out, M);
  } else {
    net_kernel<false><<<grid, BLOCK, 0, stream>>>(x, alpha, beta, a1, a2, a3,
                                                  W1, b1, wa1, W2, b2, wa2, nullptr, out, M);
  }
}